// Round 2
// baseline (2879.212 us; speedup 1.0000x reference)
//
#include <hip/hip_runtime.h>

typedef __attribute__((ext_vector_type(8))) short short8;
typedef __attribute__((ext_vector_type(4))) float floatx4;
typedef __attribute__((ext_vector_type(16))) float floatx16;
typedef unsigned int uint;
typedef unsigned short ushort;
typedef unsigned long long ull;
typedef __attribute__((ext_vector_type(4))) uint uintx4;
typedef __attribute__((ext_vector_type(4))) int intx4;

#define B_ 512
#define S_ 200
#define H_ 512
#define VOCAB_ 2002

__device__ __forceinline__ ushort f2bfbits(float f) {
  union { float f; uint u; } c; c.f = f;
  uint u = c.u;
  u += 0x7fffu + ((u >> 16) & 1u);   // RNE
  return (ushort)(u >> 16);
}
__device__ __forceinline__ float bf2f_(ushort u) {
  union { uint i; float f; } c; c.i = ((uint)u) << 16; return c.f;
}
__device__ __forceinline__ float sigmoidf_(float x) { return 1.f / (1.f + __expf(-x)); }
__device__ __forceinline__ float tanhf_(float x) { return 2.f / (1.f + __expf(-2.f * x)) - 1.f; }
__device__ __forceinline__ float clamp30(float x) { return fminf(fmaxf(x, -30.f), 30.f); }

// split f32[8] -> (hi, lo) bf16 short8 pair; hi+lo carries ~16 mantissa bits
__device__ __forceinline__ void split8(const float* p, short8& hi, short8& lo) {
#pragma unroll
  for (int j = 0; j < 8; ++j) {
    const float f = p[j];
    const ushort h = f2bfbits(f);
    hi[j] = (short)h;
    lo[j] = (short)f2bfbits(f - bf2f_(h));
  }
}

// --- coherent (agent-safe, L1/L2-bypassing) 32B load: issue only, no wait ---
__device__ __forceinline__ void ld32_cc(const void* p, uintx4& a, uintx4& b) {
  asm volatile("global_load_dwordx4 %0, %2, off sc0 sc1\n\t"
               "global_load_dwordx4 %1, %2, off offset:16 sc0 sc1"
               : "=&v"(a), "=&v"(b)
               : "v"(p));
}
// --- coherent 32B load with embedded drain (for the spin poll) ---
__device__ __forceinline__ void ld32_cc_wait(const void* p, intx4& a, intx4& b) {
  asm volatile("global_load_dwordx4 %0, %2, off sc0 sc1\n\t"
               "global_load_dwordx4 %1, %2, off offset:16 sc0 sc1\n\t"
               "s_waitcnt vmcnt(0)"
               : "=&v"(a), "=&v"(b)
               : "v"(p)
               : "memory");
}
__device__ __forceinline__ void vm_wait0() {
  asm volatile("s_waitcnt vmcnt(0)" ::: "memory");
}
__device__ __forceinline__ void vm_wait4() {
  asm volatile("s_waitcnt vmcnt(4)" ::: "memory");
}

// ---------------------------------------------------------------------------
// K1: EncGates[v][n] = emb[v]·W_ih[n]  (f32-accurate via 3-product split MFMA)
// grid (32,126) x 256 thr (4 waves, one 16x16 tile each). Biases added later.
// ---------------------------------------------------------------------------
template <typename ET>
__global__ void encg_kernel(const float* __restrict__ emb, const float* __restrict__ Wih,
                            ET* __restrict__ encg) {
  const int w = threadIdx.x >> 6, l = threadIdx.x & 63;
  const int ln = l & 15, lk = l >> 4;
  const int n = (blockIdx.x * 4 + w) * 16 + ln;
  const int m = blockIdx.y * 16 + ln;
  const int mA = (m < VOCAB_) ? m : 0;
  const float* ap = emb + (size_t)mA * 512 + lk * 8;
  const float* bp = Wih + (size_t)n * 512 + lk * 8;
  floatx4 acc = {0.f, 0.f, 0.f, 0.f};
#pragma unroll 4
  for (int kk = 0; kk < 16; ++kk) {
    short8 ah, al, bh, bl;
    split8(ap + kk * 32, ah, al);
    split8(bp + kk * 32, bh, bl);
    acc = __builtin_amdgcn_mfma_f32_16x16x32_bf16(ah, bh, acc, 0, 0, 0);
    acc = __builtin_amdgcn_mfma_f32_16x16x32_bf16(ah, bl, acc, 0, 0, 0);
    acc = __builtin_amdgcn_mfma_f32_16x16x32_bf16(al, bh, acc, 0, 0, 0);
  }
#pragma unroll
  for (int r = 0; r < 4; ++r) {
    const int mo = blockIdx.y * 16 + lk * 4 + r;   // C/D: row=(lane>>4)*4+reg
    if (mo < VOCAB_) {
      if constexpr (sizeof(ET) == 2)
        encg[(size_t)mo * 2048 + n] = (ET)f2bfbits(acc[r]);
      else
        encg[(size_t)mo * 2048 + n] = acc[r];       // col = lane&15
    }
  }
}

// ---------------------------------------------------------------------------
// K2: et[s][b] = sigmoid(P[u].Q[k] + Pb[u] + Qb[k]); f32. grid (200,128)x256.
// ---------------------------------------------------------------------------
__global__ void mf_kernel(const int* __restrict__ us, const int* __restrict__ ss,
                          const float* __restrict__ P, const float* __restrict__ Q,
                          const float* __restrict__ Pb, const float* __restrict__ Qb,
                          float* __restrict__ etb) {
  const int s = blockIdx.x;
  const int w = threadIdx.x >> 6, l = threadIdx.x & 63;
  const int b = blockIdx.y * 4 + w;
  const int u = us[b * S_ + s];
  const int k = ss[b * S_ + s];
  const float4 p0 = *(const float4*)(P + (size_t)u * 512 + l * 8);
  const float4 p1 = *(const float4*)(P + (size_t)u * 512 + l * 8 + 4);
  const float4 q0 = *(const float4*)(Q + (size_t)k * 512 + l * 8);
  const float4 q1 = *(const float4*)(Q + (size_t)k * 512 + l * 8 + 4);
  float dot = p0.x*q0.x + p0.y*q0.y + p0.z*q0.z + p0.w*q0.w
            + p1.x*q1.x + p1.y*q1.y + p1.z*q1.z + p1.w*q1.w;
#pragma unroll
  for (int off = 32; off > 0; off >>= 1) dot += __shfl_xor(dot, off);
  if (l == 0)
    etb[s * B_ + b] = sigmoidf_(dot + Pb[u] + Qb[k]);
}

// ---------------------------------------------------------------------------
// K3: recurrent LSTM, f32-accurate. 256 blocks x 512 thr, 1 block/CU.
// group g=bid&15 owns 32 batch rows; slice ns=bid>>4 owns 32 h-units.
//
// r10 changes vs r9 (sync fabric / numerics / ht layout unchanged):
//  - MFMA restructure: 32x32x16 bf16, 8 waves = 4 gate-tiles (nt) x 2 K-halves
//    (kh). Per-wave A-LDS read = 32KB (its K-half only) -> 256KB/block-step,
//    HALF of r9's 512KB. B-reg cost unchanged (128 VGPR), acc 16 f32.
//    Fragment reads verified 2/bank per 16-lane phase under the XOR swizzle.
//  - Phase-specialized waves: kh0 MFMAs cols 0..255 between barB/barC while
//    kh1 drains+writes the h1 LDS half; kh1 MFMAs between barC/barD while kh0
//    writes gp partials + its own h1 register chunks.
//  - All 8 staging loads issued up-front in a sched_barrier(0)-pinned region
//    with counted s_waitcnt vmcnt(4): h1's MALL RT hides under barB + MFMAs.
//  - gp exchange: [kh][col][33] f32; nonlin sums the two K-half partials.
//    Write banks: (l&31)+row distinct per phase; read banks 2/bank. Free.
//  - s_sleep(2) backoff in the spin poll (cuts MALL poll pressure).
// ---------------------------------------------------------------------------
template <typename ET>
__global__ __launch_bounds__(512, 2) void lstm_kernel(
    const int* __restrict__ tok, const ET* __restrict__ encg,
    const float* __restrict__ etb, const float* __restrict__ Whh,
    const float* __restrict__ bih, const float* __restrict__ bhh,
    ushort* ht_hi, ushort* ht_lo, int* ctr) {
  __shared__ __align__(16) ushort Ah_lds[32 * 512];   // 32,768 B (XOR-swizzled)
  __shared__ __align__(16) ushort Al_lds[32 * 512];   // 32,768 B
  __shared__ float gp_lds[2 * 128 * 33];              // 33,792 B

  const int bid = blockIdx.x;
  const int g = bid & 15, ns = bid >> 4;
  const int b0 = g * 32, h0 = ns * 32;
  const int tid = threadIdx.x;
  const int w = tid >> 6, l = tid & 63;
  const int nt = w & 3;                 // gate tile (i,f,g,o)
  const int kh = w >> 2;                // K-half (0: cols 0..255, 1: 256..511)

  // slots: group g's producer block ns publishes 8 wave-slots at
  // ctr[g*256 + ns*16 .. +8) -- one 64-B line per block.
  int* const myslot = ctr + g * 256 + ns * 16;
  const int* const gslots = ctr + g * 256;

  // --- preload + split this wave's W_hh rows (32 gate cols, its K-half) ---
  // B operand 32x32x16: lane l holds col=l&31, k=(l>>5)*8+j.
  short8 Bh[16], Bl[16];
  {
    const float* wr = Whh + (size_t)(nt * 512 + h0 + (l & 31)) * 512
                    + kh * 256 + (l >> 5) * 8;
#pragma unroll 4
    for (int kk = 0; kk < 16; ++kk)
      split8(wr + kk * 16, Bh[kk], Bl[kk]);
  }

  const int sr = tid >> 4;              // batch row within group (0..31)
  const int sc = tid & 15;              // 16 stagers per row
  const int hh = sc * 2;
  const int bg = b0 + sr;
  float ct0 = 0.f, ct1 = 0.f;

  float bs[4][2];
#pragma unroll
  for (int qq = 0; qq < 4; ++qq) {
    const int col = qq * 512 + h0 + hh;
    bs[qq][0] = bih[col] + bhh[col];
    bs[qq][1] = bih[col + 1] + bhh[col + 1];
  }

  const int swzw = (sr & 7) << 3;       // writer swizzle (ushort units)
  const int swzr = (l & 7) << 3;        // reader swizzle (row = l&31 -> row&7 = l&7)
  const int khbase = kh * 256;          // this wave's K-half base (ushort col)
  const int k8 = (l >> 5) * 8;          // lane's k-offset within 16-wide step

  // 48 MFMAs over one K-half; A row = l&31 from swizzled LDS.
  auto mfma_half = [&](int base) -> floatx16 {
    floatx16 a = {0.f,0.f,0.f,0.f,0.f,0.f,0.f,0.f,
                  0.f,0.f,0.f,0.f,0.f,0.f,0.f,0.f};
#pragma unroll
    for (int kk = 0; kk < 16; ++kk) {
      const int ao = (l & 31) * 512 + ((base + kk * 16 + k8) ^ swzr);
      const short8 ah = *(const short8*)(Ah_lds + ao);
      const short8 al = *(const short8*)(Al_lds + ao);
      a = __builtin_amdgcn_mfma_f32_32x32x16_bf16(ah, Bh[kk], a, 0, 0, 0);
      a = __builtin_amdgcn_mfma_f32_32x32x16_bf16(ah, Bl[kk], a, 0, 0, 0);
      a = __builtin_amdgcn_mfma_f32_32x32x16_bf16(al, Bh[kk], a, 0, 0, 0);
    }
    return a;
  };
  // C/D 32x32: col = lane&31, row = (reg&3) + 8*(reg>>2) + 4*(lane>>5)
  auto gp_write = [&](const floatx16& a) {
    float* gpw = gp_lds + kh * 4224 + (nt * 32 + (l & 31)) * 33 + 4 * (l >> 5);
#pragma unroll
    for (int r = 0; r < 16; ++r)
      gpw[(r & 3) + 8 * (r >> 2)] = a[r];
  };

  for (int s = 0; s < S_; ++s) {
    // ---- prefetch nonlinearity inputs (ht-independent; hides under spin) ----
    const int tv = tok[bg * S_ + s];
    float ev = etb[s * B_ + bg];
    float ex[4], ey[4];
#pragma unroll
    for (int qq = 0; qq < 4; ++qq) {
      if constexpr (sizeof(ET) == 2) {
        const uint e2 = *(const uint*)((const ushort*)encg + (size_t)tv * 2048 + qq * 512 + h0 + hh);
        ex[qq] = bf2f_((ushort)(e2 & 0xffffu)); ey[qq] = bf2f_((ushort)(e2 >> 16));
      } else {
        const float2 e = *(const float2*)((const float*)encg + (size_t)tv * 2048 + qq * 512 + h0 + hh);
        ex[qq] = e.x; ey[qq] = e.y;
      }
    }

    // ---- wait for all 16 producers (8 wave-slots each) to reach step s ----
    if (s > 0 && tid < 16) {
      const int* sp = gslots + tid * 16;
      for (;;) {
        intx4 va, vb;
        ld32_cc_wait(sp, va, vb);
        if (va[0] >= s && va[1] >= s && va[2] >= s && va[3] >= s &&
            vb[0] >= s && vb[1] >= s && vb[2] >= s && vb[3] >= s) break;
        __builtin_amdgcn_s_sleep(2);   // back off: cut MALL poll pressure
      }
    }
    __syncthreads();                                     // bar A

    const size_t rdo = (size_t)(s & 1) * (B_ * H_);
    const size_t wro = (size_t)((s & 1) ^ 1) * (B_ * H_);
    const ushort* hrow = ht_hi + rdo + (size_t)bg * 512;
    const ushort* lrow = ht_lo + rdo + (size_t)bg * 512;

    // ---- issue ALL staging loads; counted wait drains h0 only (pinned) ----
    const int c0 = sc * 16, c1 = 256 + sc * 16;
    uintx4 h00, h01, l00, l01;          // h0 chunks
    uintx4 nh0, nh1, nl0, nl1;          // h1 chunks (written later)
    __builtin_amdgcn_sched_barrier(0);
    ld32_cc(hrow + c0, h00, h01);
    ld32_cc(lrow + c0, l00, l01);
    ld32_cc(hrow + c1, nh0, nh1);
    ld32_cc(lrow + c1, nl0, nl1);
    vm_wait4();                          // oldest 4 (h0) complete
    __builtin_amdgcn_sched_barrier(0);
    {
      const int d0 = sr * 512 + (c0 ^ swzw);
      const int d1 = sr * 512 + ((c0 + 8) ^ swzw);
      *(uintx4*)(Ah_lds + d0) = h00; *(uintx4*)(Ah_lds + d1) = h01;
      *(uintx4*)(Al_lds + d0) = l00; *(uintx4*)(Al_lds + d1) = l01;
    }
    __syncthreads();                                     // bar B (h0 staged)

    floatx16 acc;
    if (kh == 0) {
      acc = mfma_half(0);               // reads h0 half of LDS
      gp_write(acc);
      vm_wait0();                        // h1 long since arrived
      __builtin_amdgcn_sched_barrier(0);
      const int e0 = sr * 512 + (c1 ^ swzw);
      const int e1 = sr * 512 + ((c1 + 8) ^ swzw);
      *(uintx4*)(Ah_lds + e0) = nh0; *(uintx4*)(Ah_lds + e1) = nh1;
      *(uintx4*)(Al_lds + e0) = nl0; *(uintx4*)(Al_lds + e1) = nl1;
    } else {
      vm_wait0();
      __builtin_amdgcn_sched_barrier(0);
      const int e0 = sr * 512 + (c1 ^ swzw);
      const int e1 = sr * 512 + ((c1 + 8) ^ swzw);
      *(uintx4*)(Ah_lds + e0) = nh0; *(uintx4*)(Ah_lds + e1) = nh1;
      *(uintx4*)(Al_lds + e0) = nl0; *(uintx4*)(Al_lds + e1) = nl1;
    }
    __syncthreads();                                     // bar C (h1 staged)

    if (kh == 1) {
      acc = mfma_half(256);             // reads h1 half of LDS
      gp_write(acc);
    }
    __syncthreads();                                     // bar D (gp complete)

    // ---- nonlinearity: thread owns (row sr, h-units hh, hh+1) ----
    {
      ev = fminf(fmaxf(ev, 0.f), 1.f);
      float Gv[4][2];
#pragma unroll
      for (int qq = 0; qq < 4; ++qq) {
        const int cb0 = (qq * 32 + hh) * 33 + sr;
        const int cb1 = (qq * 32 + hh + 1) * 33 + sr;
        Gv[qq][0] = clamp30(gp_lds[cb0] + gp_lds[4224 + cb0] + ex[qq] + bs[qq][0]);
        Gv[qq][1] = clamp30(gp_lds[cb1] + gp_lds[4224 + cb1] + ey[qq] + bs[qq][1]);
      }
      const float scale = 1.f + ev;
      float c0v = ct0 * scale;
      c0v = sigmoidf_(Gv[1][0]) * c0v + sigmoidf_(Gv[0][0]) * tanhf_(Gv[2][0]);
      const float h0v = sigmoidf_(Gv[3][0]) * tanhf_(c0v);
      ct0 = c0v;                                   // UNCLAMPED (ref semantics)
      float c1v = ct1 * scale;
      c1v = sigmoidf_(Gv[1][1]) * c1v + sigmoidf_(Gv[0][1]) * tanhf_(Gv[2][1]);
      const float h1v = sigmoidf_(Gv[3][1]) * tanhf_(c1v);
      ct1 = c1v;
      const ushort h0h = f2bfbits(h0v), h1h = f2bfbits(h1v);
      const ushort h0l = f2bfbits(h0v - bf2f_(h0h)), h1l = f2bfbits(h1v - bf2f_(h1h));
      const size_t wo = wro + (size_t)bg * 512 + h0 + hh;
      __hip_atomic_store((uint*)(ht_hi + wo), (uint)h0h | ((uint)h1h << 16),
                         __ATOMIC_RELAXED, __HIP_MEMORY_SCOPE_AGENT);
      __hip_atomic_store((uint*)(ht_lo + wo), (uint)h0l | ((uint)h1l << 16),
                         __ATOMIC_RELAXED, __HIP_MEMORY_SCOPE_AGENT);
    }

    // ---- per-wave publish: drain THIS wave's ht stores, then set wave-slot.
    vm_wait0();
    if (l == 0)
      __hip_atomic_store(myslot + w, s + 1, __ATOMIC_RELAXED, __HIP_MEMORY_SCOPE_AGENT);
  }
}

// ---------------------------------------------------------------------------
// K4: out[b] = sigmoid( (ht_hi+ht_lo)[b] . dec_W[tgt[b]] + dec_b[tgt[b]] )
// grid 128 x 256 (one wave per batch row). Final ht is in buffer parity 0.
// ---------------------------------------------------------------------------
__global__ void dec_kernel(const ushort* __restrict__ hthi, const ushort* __restrict__ htlo,
                           const float* __restrict__ decW, const float* __restrict__ decb,
                           const int* __restrict__ tgt, float* __restrict__ out) {
  const int w = threadIdx.x >> 6, l = threadIdx.x & 63;
  const int b = blockIdx.x * 4 + w;
  const int t = tgt[b];
  const uint4 hv = *(const uint4*)(hthi + (size_t)b * 512 + l * 8);
  const uint4 lv = *(const uint4*)(htlo + (size_t)b * 512 + l * 8);
  const float4 w0 = *(const float4*)(decW + (size_t)t * 512 + l * 8);
  const float4 w1 = *(const float4*)(decW + (size_t)t * 512 + l * 8 + 4);
  const uint ha[4] = {hv.x, hv.y, hv.z, hv.w};
  const uint la[4] = {lv.x, lv.y, lv.z, lv.w};
  float hf[8];
#pragma unroll
  for (int i = 0; i < 4; ++i) {
    hf[2*i]   = bf2f_((ushort)(ha[i] & 0xffffu)) + bf2f_((ushort)(la[i] & 0xffffu));
    hf[2*i+1] = bf2f_((ushort)(ha[i] >> 16))     + bf2f_((ushort)(la[i] >> 16));
  }
  float dot = hf[0]*w0.x + hf[1]*w0.y + hf[2]*w0.z + hf[3]*w0.w
            + hf[4]*w1.x + hf[5]*w1.y + hf[6]*w1.z + hf[7]*w1.w;
#pragma unroll
  for (int off = 32; off > 0; off >>= 1) dot += __shfl_xor(dot, off);
  if (l == 0) out[b] = sigmoidf_(dot + decb[t]);
}

extern "C" void kernel_launch(void* const* d_in, const int* in_sizes, int n_in,
                              void* d_out, int out_size, void* d_ws, size_t ws_size,
                              hipStream_t stream) {
  (void)in_sizes; (void)n_in; (void)out_size;
  const int* main_input = (const int*)d_in[0];
  const int* target_id  = (const int*)d_in[1];
  const int* user_seq   = (const int*)d_in[2];
  const int* skill_seq  = (const int*)d_in[3];
  const float* enc_emb  = (const float*)d_in[4];
  const float* P        = (const float*)d_in[5];
  const float* Q        = (const float*)d_in[6];
  const float* Pb       = (const float*)d_in[7];
  const float* Qb       = (const float*)d_in[8];
  const float* W_ih     = (const float*)d_in[9];
  const float* W_hh     = (const float*)d_in[10];
  const float* b_ih     = (const float*)d_in[11];
  const float* b_hh     = (const float*)d_in[12];
  const float* dec_W    = (const float*)d_in[13];
  const float* dec_b    = (const float*)d_in[14];
  float* out = (float*)d_out;

  // workspace layout (unchanged):
  //   [0)          ht_hi  2*512*512 bf16 = 1,048,576
  //   [1,048,576)  ht_lo  1,048,576                  -> 2,097,152
  //   [2,097,152)  ctr    256 slots x 64 B = 16,384  -> 2,113,536
  //   [2,113,536)  etb    200*512 f32 = 409,600      -> 2,523,136
  //   [2,523,136)  encg   f32 16,400,384 (else bf16 8,200,192)
  char* wsb = (char*)d_ws;
  ushort* ht_hi = (ushort*)wsb;
  ushort* ht_lo = (ushort*)(wsb + 1048576);
  int* ctr = (int*)(wsb + 2097152);
  float* etb = (float*)(wsb + 2113536);
  char* encb = wsb + 2523136;
  const bool enc32 = ws_size >= (size_t)2523136 + 16400384;

  hipMemsetAsync(wsb, 0, 2113536, stream);   // ht(0)=0, all slots=0

  if (enc32)
    encg_kernel<float><<<dim3(32, 126), dim3(256), 0, stream>>>(enc_emb, W_ih, (float*)encb);
  else
    encg_kernel<ushort><<<dim3(32, 126), dim3(256), 0, stream>>>(enc_emb, W_ih, (ushort*)encb);
  mf_kernel<<<dim3(200, 128), dim3(256), 0, stream>>>(user_seq, skill_seq, P, Q, Pb, Qb, etb);
  if (enc32)
    lstm_kernel<float><<<dim3(256), dim3(512), 0, stream>>>(
        main_input, (const float*)encb, etb, W_hh, b_ih, b_hh, ht_hi, ht_lo, ctr);
  else
    lstm_kernel<ushort><<<dim3(256), dim3(512), 0, stream>>>(
        main_input, (const ushort*)encb, etb, W_hh, b_ih, b_hh, ht_hi, ht_lo, ctr);
  dec_kernel<<<dim3(128), dim3(256), 0, stream>>>(ht_hi, ht_lo, dec_W, dec_b, target_id, out);
}

// Round 3
// 2734.561 us; speedup vs baseline: 1.0529x; 1.0529x over previous
//
#include <hip/hip_runtime.h>

typedef __attribute__((ext_vector_type(8))) short short8;
typedef __attribute__((ext_vector_type(4))) float floatx4;
typedef __attribute__((ext_vector_type(16))) float floatx16;
typedef unsigned int uint;
typedef unsigned short ushort;
typedef unsigned long long ull;
typedef __attribute__((ext_vector_type(4))) uint uintx4;
typedef __attribute__((ext_vector_type(4))) int intx4;

#define B_ 512
#define S_ 200
#define H_ 512
#define VOCAB_ 2002

__device__ __forceinline__ ushort f2bfbits(float f) {
  union { float f; uint u; } c; c.f = f;
  uint u = c.u;
  u += 0x7fffu + ((u >> 16) & 1u);   // RNE
  return (ushort)(u >> 16);
}
__device__ __forceinline__ float bf2f_(ushort u) {
  union { uint i; float f; } c; c.i = ((uint)u) << 16; return c.f;
}
__device__ __forceinline__ float sigmoidf_(float x) { return 1.f / (1.f + __expf(-x)); }
__device__ __forceinline__ float tanhf_(float x) { return 2.f / (1.f + __expf(-2.f * x)) - 1.f; }
__device__ __forceinline__ float clamp30(float x) { return fminf(fmaxf(x, -30.f), 30.f); }

// split f32[8] -> (hi, lo) bf16 short8 pair; hi+lo carries ~16 mantissa bits
__device__ __forceinline__ void split8(const float* p, short8& hi, short8& lo) {
#pragma unroll
  for (int j = 0; j < 8; ++j) {
    const float f = p[j];
    const ushort h = f2bfbits(f);
    hi[j] = (short)h;
    lo[j] = (short)f2bfbits(f - bf2f_(h));
  }
}

// --- coherent (agent-safe, L1/L2-bypassing) 32B load: issue only, no wait ---
__device__ __forceinline__ void ld32_cc(const void* p, uintx4& a, uintx4& b) {
  asm volatile("global_load_dwordx4 %0, %2, off sc0 sc1\n\t"
               "global_load_dwordx4 %1, %2, off offset:16 sc0 sc1"
               : "=&v"(a), "=&v"(b)
               : "v"(p));
}
// --- coherent 4B load with embedded drain (spin poll; 16 lanes = 1 request) ---
__device__ __forceinline__ int ld4_cc_wait(const int* p) {
  int v;
  asm volatile("global_load_dword %0, %1, off sc0 sc1\n\t"
               "s_waitcnt vmcnt(0)"
               : "=v"(v)
               : "v"(p)
               : "memory");
  return v;
}
__device__ __forceinline__ void vm_wait0() {
  asm volatile("s_waitcnt vmcnt(0)" ::: "memory");
}
__device__ __forceinline__ void vm_wait4() {
  asm volatile("s_waitcnt vmcnt(4)" ::: "memory");
}

// ---------------------------------------------------------------------------
// K1: EncGates[v][n] = emb[v]·W_ih[n]  (f32-accurate via 3-product split MFMA)
// grid (32,126) x 256 thr (4 waves, one 16x16 tile each). Biases added later.
// ---------------------------------------------------------------------------
template <typename ET>
__global__ void encg_kernel(const float* __restrict__ emb, const float* __restrict__ Wih,
                            ET* __restrict__ encg) {
  const int w = threadIdx.x >> 6, l = threadIdx.x & 63;
  const int ln = l & 15, lk = l >> 4;
  const int n = (blockIdx.x * 4 + w) * 16 + ln;
  const int m = blockIdx.y * 16 + ln;
  const int mA = (m < VOCAB_) ? m : 0;
  const float* ap = emb + (size_t)mA * 512 + lk * 8;
  const float* bp = Wih + (size_t)n * 512 + lk * 8;
  floatx4 acc = {0.f, 0.f, 0.f, 0.f};
#pragma unroll 4
  for (int kk = 0; kk < 16; ++kk) {
    short8 ah, al, bh, bl;
    split8(ap + kk * 32, ah, al);
    split8(bp + kk * 32, bh, bl);
    acc = __builtin_amdgcn_mfma_f32_16x16x32_bf16(ah, bh, acc, 0, 0, 0);
    acc = __builtin_amdgcn_mfma_f32_16x16x32_bf16(ah, bl, acc, 0, 0, 0);
    acc = __builtin_amdgcn_mfma_f32_16x16x32_bf16(al, bh, acc, 0, 0, 0);
  }
#pragma unroll
  for (int r = 0; r < 4; ++r) {
    const int mo = blockIdx.y * 16 + lk * 4 + r;   // C/D: row=(lane>>4)*4+reg
    if (mo < VOCAB_) {
      if constexpr (sizeof(ET) == 2)
        encg[(size_t)mo * 2048 + n] = (ET)f2bfbits(acc[r]);
      else
        encg[(size_t)mo * 2048 + n] = acc[r];       // col = lane&15
    }
  }
}

// ---------------------------------------------------------------------------
// K2: et[s][b] = sigmoid(P[u].Q[k] + Pb[u] + Qb[k]); f32. grid (200,128)x256.
// ---------------------------------------------------------------------------
__global__ void mf_kernel(const int* __restrict__ us, const int* __restrict__ ss,
                          const float* __restrict__ P, const float* __restrict__ Q,
                          const float* __restrict__ Pb, const float* __restrict__ Qb,
                          float* __restrict__ etb) {
  const int s = blockIdx.x;
  const int w = threadIdx.x >> 6, l = threadIdx.x & 63;
  const int b = blockIdx.y * 4 + w;
  const int u = us[b * S_ + s];
  const int k = ss[b * S_ + s];
  const float4 p0 = *(const float4*)(P + (size_t)u * 512 + l * 8);
  const float4 p1 = *(const float4*)(P + (size_t)u * 512 + l * 8 + 4);
  const float4 q0 = *(const float4*)(Q + (size_t)k * 512 + l * 8);
  const float4 q1 = *(const float4*)(Q + (size_t)k * 512 + l * 8 + 4);
  float dot = p0.x*q0.x + p0.y*q0.y + p0.z*q0.z + p0.w*q0.w
            + p1.x*q1.x + p1.y*q1.y + p1.z*q1.z + p1.w*q1.w;
#pragma unroll
  for (int off = 32; off > 0; off >>= 1) dot += __shfl_xor(dot, off);
  if (l == 0)
    etb[s * B_ + b] = sigmoidf_(dot + Pb[u] + Qb[k]);
}

// ---------------------------------------------------------------------------
// K3: recurrent LSTM, f32-accurate. 256 blocks x 512 thr, 1 block/CU.
// group g=bid&15 owns 32 batch rows; slice ns=bid>>4 owns 32 h-units.
//
// r11 changes vs r10 (compute/staging structure byte-identical to r10):
//  - SYNC FABRIC: per-BLOCK slot again, but all 16 slots of a group PACKED
//    into ONE 64-B line (plain relaxed 4B stores to distinct dwords; no RMW).
//    Consumer poll: 16 lanes x 1 dword from that line = ONE 64B request per
//    iteration (was 16 lanes x 64B = 1KB). r10's poll was ~2.9GB of the
//    7.55GB total FETCH and queued against staging on the same MALL path.
//  - publish: explicit vmcnt(0) + __syncthreads (all waves drained to the
//    coherence point), then ONE tid0 store. Visibility argument as r8.
//  - s_sleep removed from poll (traffic now negligible; latency wins).
// ---------------------------------------------------------------------------
template <typename ET>
__global__ __launch_bounds__(512, 2) void lstm_kernel(
    const int* __restrict__ tok, const ET* __restrict__ encg,
    const float* __restrict__ etb, const float* __restrict__ Whh,
    const float* __restrict__ bih, const float* __restrict__ bhh,
    ushort* ht_hi, ushort* ht_lo, int* ctr) {
  __shared__ __align__(16) ushort Ah_lds[32 * 512];   // 32,768 B (XOR-swizzled)
  __shared__ __align__(16) ushort Al_lds[32 * 512];   // 32,768 B
  __shared__ float gp_lds[2 * 128 * 33];              // 33,792 B

  const int bid = blockIdx.x;
  const int g = bid & 15, ns = bid >> 4;
  const int b0 = g * 32, h0 = ns * 32;
  const int tid = threadIdx.x;
  const int w = tid >> 6, l = tid & 63;
  const int nt = w & 3;                 // gate tile (i,f,g,o)
  const int kh = w >> 2;                // K-half (0: cols 0..255, 1: 256..511)

  // slots: group g's 16 producer blocks publish at ctr[g*16 + ns] -- one
  // 64-B line per group, one dword per block.
  int* const myslot = ctr + g * 16 + ns;
  const int* const gslots = ctr + g * 16;

  // --- preload + split this wave's W_hh rows (32 gate cols, its K-half) ---
  // B operand 32x32x16: lane l holds col=l&31, k=(l>>5)*8+j.
  short8 Bh[16], Bl[16];
  {
    const float* wr = Whh + (size_t)(nt * 512 + h0 + (l & 31)) * 512
                    + kh * 256 + (l >> 5) * 8;
#pragma unroll 4
    for (int kk = 0; kk < 16; ++kk)
      split8(wr + kk * 16, Bh[kk], Bl[kk]);
  }

  const int sr = tid >> 4;              // batch row within group (0..31)
  const int sc = tid & 15;              // 16 stagers per row
  const int hh = sc * 2;
  const int bg = b0 + sr;
  float ct0 = 0.f, ct1 = 0.f;

  float bs[4][2];
#pragma unroll
  for (int qq = 0; qq < 4; ++qq) {
    const int col = qq * 512 + h0 + hh;
    bs[qq][0] = bih[col] + bhh[col];
    bs[qq][1] = bih[col + 1] + bhh[col + 1];
  }

  const int swzw = (sr & 7) << 3;       // writer swizzle (ushort units)
  const int swzr = (l & 7) << 3;        // reader swizzle (row = l&31 -> row&7 = l&7)
  const int k8 = (l >> 5) * 8;          // lane's k-offset within 16-wide step

  // 48 MFMAs over one K-half; A row = l&31 from swizzled LDS.
  auto mfma_half = [&](int base) -> floatx16 {
    floatx16 a = {0.f,0.f,0.f,0.f,0.f,0.f,0.f,0.f,
                  0.f,0.f,0.f,0.f,0.f,0.f,0.f,0.f};
#pragma unroll
    for (int kk = 0; kk < 16; ++kk) {
      const int ao = (l & 31) * 512 + ((base + kk * 16 + k8) ^ swzr);
      const short8 ah = *(const short8*)(Ah_lds + ao);
      const short8 al = *(const short8*)(Al_lds + ao);
      a = __builtin_amdgcn_mfma_f32_32x32x16_bf16(ah, Bh[kk], a, 0, 0, 0);
      a = __builtin_amdgcn_mfma_f32_32x32x16_bf16(ah, Bl[kk], a, 0, 0, 0);
      a = __builtin_amdgcn_mfma_f32_32x32x16_bf16(al, Bh[kk], a, 0, 0, 0);
    }
    return a;
  };
  // C/D 32x32: col = lane&31, row = (reg&3) + 8*(reg>>2) + 4*(lane>>5)
  auto gp_write = [&](const floatx16& a) {
    float* gpw = gp_lds + kh * 4224 + (nt * 32 + (l & 31)) * 33 + 4 * (l >> 5);
#pragma unroll
    for (int r = 0; r < 16; ++r)
      gpw[(r & 3) + 8 * (r >> 2)] = a[r];
  };

  for (int s = 0; s < S_; ++s) {
    // ---- prefetch nonlinearity inputs (ht-independent; hides under spin) ----
    const int tv = tok[bg * S_ + s];
    float ev = etb[s * B_ + bg];
    float ex[4], ey[4];
#pragma unroll
    for (int qq = 0; qq < 4; ++qq) {
      if constexpr (sizeof(ET) == 2) {
        const uint e2 = *(const uint*)((const ushort*)encg + (size_t)tv * 2048 + qq * 512 + h0 + hh);
        ex[qq] = bf2f_((ushort)(e2 & 0xffffu)); ey[qq] = bf2f_((ushort)(e2 >> 16));
      } else {
        const float2 e = *(const float2*)((const float*)encg + (size_t)tv * 2048 + qq * 512 + h0 + hh);
        ex[qq] = e.x; ey[qq] = e.y;
      }
    }

    // ---- wait: all 16 producer blocks of this group must have published s.
    // One 64B line; lane tid polls dword tid -> one coalesced request/iter.
    if (s > 0 && tid < 16) {
      const int* sp = gslots + tid;
      while (ld4_cc_wait(sp) < s) {}
    }
    __syncthreads();                                     // bar A

    const size_t rdo = (size_t)(s & 1) * (B_ * H_);
    const size_t wro = (size_t)((s & 1) ^ 1) * (B_ * H_);
    const ushort* hrow = ht_hi + rdo + (size_t)bg * 512;
    const ushort* lrow = ht_lo + rdo + (size_t)bg * 512;

    // ---- issue ALL staging loads; counted wait drains h0 only (pinned) ----
    const int c0 = sc * 16, c1 = 256 + sc * 16;
    uintx4 h00, h01, l00, l01;          // h0 chunks
    uintx4 nh0, nh1, nl0, nl1;          // h1 chunks (written later)
    __builtin_amdgcn_sched_barrier(0);
    ld32_cc(hrow + c0, h00, h01);
    ld32_cc(lrow + c0, l00, l01);
    ld32_cc(hrow + c1, nh0, nh1);
    ld32_cc(lrow + c1, nl0, nl1);
    vm_wait4();                          // oldest 4 (h0) complete
    __builtin_amdgcn_sched_barrier(0);
    {
      const int d0 = sr * 512 + (c0 ^ swzw);
      const int d1 = sr * 512 + ((c0 + 8) ^ swzw);
      *(uintx4*)(Ah_lds + d0) = h00; *(uintx4*)(Ah_lds + d1) = h01;
      *(uintx4*)(Al_lds + d0) = l00; *(uintx4*)(Al_lds + d1) = l01;
    }
    __syncthreads();                                     // bar B (h0 staged)

    floatx16 acc;
    if (kh == 0) {
      acc = mfma_half(0);               // reads h0 half of LDS
      gp_write(acc);
      vm_wait0();                        // h1 long since arrived
      __builtin_amdgcn_sched_barrier(0);
      const int e0 = sr * 512 + (c1 ^ swzw);
      const int e1 = sr * 512 + ((c1 + 8) ^ swzw);
      *(uintx4*)(Ah_lds + e0) = nh0; *(uintx4*)(Ah_lds + e1) = nh1;
      *(uintx4*)(Al_lds + e0) = nl0; *(uintx4*)(Al_lds + e1) = nl1;
    } else {
      vm_wait0();
      __builtin_amdgcn_sched_barrier(0);
      const int e0 = sr * 512 + (c1 ^ swzw);
      const int e1 = sr * 512 + ((c1 + 8) ^ swzw);
      *(uintx4*)(Ah_lds + e0) = nh0; *(uintx4*)(Ah_lds + e1) = nh1;
      *(uintx4*)(Al_lds + e0) = nl0; *(uintx4*)(Al_lds + e1) = nl1;
    }
    __syncthreads();                                     // bar C (h1 staged)

    if (kh == 1) {
      acc = mfma_half(256);             // reads h1 half of LDS
      gp_write(acc);
    }
    __syncthreads();                                     // bar D (gp complete)

    // ---- nonlinearity: thread owns (row sr, h-units hh, hh+1) ----
    {
      ev = fminf(fmaxf(ev, 0.f), 1.f);
      float Gv[4][2];
#pragma unroll
      for (int qq = 0; qq < 4; ++qq) {
        const int cb0 = (qq * 32 + hh) * 33 + sr;
        const int cb1 = (qq * 32 + hh + 1) * 33 + sr;
        Gv[qq][0] = clamp30(gp_lds[cb0] + gp_lds[4224 + cb0] + ex[qq] + bs[qq][0]);
        Gv[qq][1] = clamp30(gp_lds[cb1] + gp_lds[4224 + cb1] + ey[qq] + bs[qq][1]);
      }
      const float scale = 1.f + ev;
      float c0v = ct0 * scale;
      c0v = sigmoidf_(Gv[1][0]) * c0v + sigmoidf_(Gv[0][0]) * tanhf_(Gv[2][0]);
      const float h0v = sigmoidf_(Gv[3][0]) * tanhf_(c0v);
      ct0 = c0v;                                   // UNCLAMPED (ref semantics)
      float c1v = ct1 * scale;
      c1v = sigmoidf_(Gv[1][1]) * c1v + sigmoidf_(Gv[0][1]) * tanhf_(Gv[2][1]);
      const float h1v = sigmoidf_(Gv[3][1]) * tanhf_(c1v);
      ct1 = c1v;
      const ushort h0h = f2bfbits(h0v), h1h = f2bfbits(h1v);
      const ushort h0l = f2bfbits(h0v - bf2f_(h0h)), h1l = f2bfbits(h1v - bf2f_(h1h));
      const size_t wo = wro + (size_t)bg * 512 + h0 + hh;
      __hip_atomic_store((uint*)(ht_hi + wo), (uint)h0h | ((uint)h1h << 16),
                         __ATOMIC_RELAXED, __HIP_MEMORY_SCOPE_AGENT);
      __hip_atomic_store((uint*)(ht_lo + wo), (uint)h0l | ((uint)h1l << 16),
                         __ATOMIC_RELAXED, __HIP_MEMORY_SCOPE_AGENT);
    }

    // ---- per-block publish: every wave drains its ht stores to the
    // coherence point (vmcnt0), barrier proves ALL waves drained, then one
    // tid0 store flips the group-visible slot to s+1.
    vm_wait0();
    __syncthreads();                                     // bar E (all drained)
    if (tid == 0)
      __hip_atomic_store(myslot, s + 1, __ATOMIC_RELAXED, __HIP_MEMORY_SCOPE_AGENT);
  }
}

// ---------------------------------------------------------------------------
// K4: out[b] = sigmoid( (ht_hi+ht_lo)[b] . dec_W[tgt[b]] + dec_b[tgt[b]] )
// grid 128 x 256 (one wave per batch row). Final ht is in buffer parity 0.
// ---------------------------------------------------------------------------
__global__ void dec_kernel(const ushort* __restrict__ hthi, const ushort* __restrict__ htlo,
                           const float* __restrict__ decW, const float* __restrict__ decb,
                           const int* __restrict__ tgt, float* __restrict__ out) {
  const int w = threadIdx.x >> 6, l = threadIdx.x & 63;
  const int b = blockIdx.x * 4 + w;
  const int t = tgt[b];
  const uint4 hv = *(const uint4*)(hthi + (size_t)b * 512 + l * 8);
  const uint4 lv = *(const uint4*)(htlo + (size_t)b * 512 + l * 8);
  const float4 w0 = *(const float4*)(decW + (size_t)t * 512 + l * 8);
  const float4 w1 = *(const float4*)(decW + (size_t)t * 512 + l * 8 + 4);
  const uint ha[4] = {hv.x, hv.y, hv.z, hv.w};
  const uint la[4] = {lv.x, lv.y, lv.z, lv.w};
  float hf[8];
#pragma unroll
  for (int i = 0; i < 4; ++i) {
    hf[2*i]   = bf2f_((ushort)(ha[i] & 0xffffu)) + bf2f_((ushort)(la[i] & 0xffffu));
    hf[2*i+1] = bf2f_((ushort)(ha[i] >> 16))     + bf2f_((ushort)(la[i] >> 16));
  }
  float dot = hf[0]*w0.x + hf[1]*w0.y + hf[2]*w0.z + hf[3]*w0.w
            + hf[4]*w1.x + hf[5]*w1.y + hf[6]*w1.z + hf[7]*w1.w;
#pragma unroll
  for (int off = 32; off > 0; off >>= 1) dot += __shfl_xor(dot, off);
  if (l == 0) out[b] = sigmoidf_(dot + decb[t]);
}

extern "C" void kernel_launch(void* const* d_in, const int* in_sizes, int n_in,
                              void* d_out, int out_size, void* d_ws, size_t ws_size,
                              hipStream_t stream) {
  (void)in_sizes; (void)n_in; (void)out_size;
  const int* main_input = (const int*)d_in[0];
  const int* target_id  = (const int*)d_in[1];
  const int* user_seq   = (const int*)d_in[2];
  const int* skill_seq  = (const int*)d_in[3];
  const float* enc_emb  = (const float*)d_in[4];
  const float* P        = (const float*)d_in[5];
  const float* Q        = (const float*)d_in[6];
  const float* Pb       = (const float*)d_in[7];
  const float* Qb       = (const float*)d_in[8];
  const float* W_ih     = (const float*)d_in[9];
  const float* W_hh     = (const float*)d_in[10];
  const float* b_ih     = (const float*)d_in[11];
  const float* b_hh     = (const float*)d_in[12];
  const float* dec_W    = (const float*)d_in[13];
  const float* dec_b    = (const float*)d_in[14];
  float* out = (float*)d_out;

  // workspace layout (unchanged):
  //   [0)          ht_hi  2*512*512 bf16 = 1,048,576
  //   [1,048,576)  ht_lo  1,048,576                  -> 2,097,152
  //   [2,097,152)  ctr    256 ints used (16 lines)   -> 2,113,536 (region)
  //   [2,113,536)  etb    200*512 f32 = 409,600      -> 2,523,136
  //   [2,523,136)  encg   f32 16,400,384 (else bf16 8,200,192)
  char* wsb = (char*)d_ws;
  ushort* ht_hi = (ushort*)wsb;
  ushort* ht_lo = (ushort*)(wsb + 1048576);
  int* ctr = (int*)(wsb + 2097152);
  float* etb = (float*)(wsb + 2113536);
  char* encb = wsb + 2523136;
  const bool enc32 = ws_size >= (size_t)2523136 + 16400384;

  hipMemsetAsync(wsb, 0, 2113536, stream);   // ht(0)=0, all slots=0

  if (enc32)
    encg_kernel<float><<<dim3(32, 126), dim3(256), 0, stream>>>(enc_emb, W_ih, (float*)encb);
  else
    encg_kernel<ushort><<<dim3(32, 126), dim3(256), 0, stream>>>(enc_emb, W_ih, (ushort*)encb);
  mf_kernel<<<dim3(200, 128), dim3(256), 0, stream>>>(user_seq, skill_seq, P, Q, Pb, Qb, etb);
  if (enc32)
    lstm_kernel<float><<<dim3(256), dim3(512), 0, stream>>>(
        main_input, (const float*)encb, etb, W_hh, b_ih, b_hh, ht_hi, ht_lo, ctr);
  else
    lstm_kernel<ushort><<<dim3(256), dim3(512), 0, stream>>>(
        main_input, (const ushort*)encb, etb, W_hh, b_ih, b_hh, ht_hi, ht_lo, ctr);
  dec_kernel<<<dim3(128), dim3(256), 0, stream>>>(ht_hi, ht_lo, dec_W, dec_b, target_id, out);
}

// Round 6
// 2672.884 us; speedup vs baseline: 1.0772x; 1.0231x over previous
//
#include <hip/hip_runtime.h>

typedef __attribute__((ext_vector_type(8))) short short8;
typedef __attribute__((ext_vector_type(4))) float floatx4;
typedef __attribute__((ext_vector_type(16))) float floatx16;
typedef unsigned int uint;
typedef unsigned short ushort;
typedef unsigned long long ull;
typedef __attribute__((ext_vector_type(4))) uint uintx4;
typedef __attribute__((ext_vector_type(4))) int intx4;

#define B_ 512
#define S_ 200
#define H_ 512
#define VOCAB_ 2002

__device__ __forceinline__ ushort f2bfbits(float f) {
  union { float f; uint u; } c; c.f = f;
  uint u = c.u;
  u += 0x7fffu + ((u >> 16) & 1u);   // RNE
  return (ushort)(u >> 16);
}
__device__ __forceinline__ float bf2f_(ushort u) {
  union { uint i; float f; } c; c.i = ((uint)u) << 16; return c.f;
}
__device__ __forceinline__ float sigmoidf_(float x) { return 1.f / (1.f + __expf(-x)); }
__device__ __forceinline__ float tanhf_(float x) { return 2.f / (1.f + __expf(-2.f * x)) - 1.f; }
__device__ __forceinline__ float clamp30(float x) { return fminf(fmaxf(x, -30.f), 30.f); }

// split f32[8] -> (hi, lo) bf16 short8 pair; hi+lo carries ~16 mantissa bits
__device__ __forceinline__ void split8(const float* p, short8& hi, short8& lo) {
#pragma unroll
  for (int j = 0; j < 8; ++j) {
    const float f = p[j];
    const ushort h = f2bfbits(f);
    hi[j] = (short)h;
    lo[j] = (short)f2bfbits(f - bf2f_(h));
  }
}

// --- coherent (agent-safe, cache-bypassing) 16B load: issue only, no wait ---
__device__ __forceinline__ void ld16_cc(const void* p, uintx4& a) {
  asm volatile("global_load_dwordx4 %0, %1, off sc0 sc1"
               : "=&v"(a)
               : "v"(p));
}
// --- coherent 4B load with embedded drain (spin poll; 16 lanes = 1 line) ---
__device__ __forceinline__ int ld4_cc_wait(const int* p) {
  int v;
  asm volatile("global_load_dword %0, %1, off sc0 sc1\n\t"
               "s_waitcnt vmcnt(0)"
               : "=v"(v)
               : "v"(p)
               : "memory");
  return v;
}
__device__ __forceinline__ void vm_wait0() {
  asm volatile("s_waitcnt vmcnt(0)" ::: "memory");
}
__device__ __forceinline__ void vm_wait4() {
  asm volatile("s_waitcnt vmcnt(4)" ::: "memory");
}

// ---------------------------------------------------------------------------
// K1: EncGates[v][n] = emb[v]·W_ih[n]  (f32-accurate via 3-product split MFMA)
// grid (32,126) x 256 thr (4 waves, one 16x16 tile each). Biases added later.
// ---------------------------------------------------------------------------
template <typename ET>
__global__ void encg_kernel(const float* __restrict__ emb, const float* __restrict__ Wih,
                            ET* __restrict__ encg) {
  const int w = threadIdx.x >> 6, l = threadIdx.x & 63;
  const int ln = l & 15, lk = l >> 4;
  const int n = (blockIdx.x * 4 + w) * 16 + ln;
  const int m = blockIdx.y * 16 + ln;
  const int mA = (m < VOCAB_) ? m : 0;
  const float* ap = emb + (size_t)mA * 512 + lk * 8;
  const float* bp = Wih + (size_t)n * 512 + lk * 8;
  floatx4 acc = {0.f, 0.f, 0.f, 0.f};
#pragma unroll 4
  for (int kk = 0; kk < 16; ++kk) {
    short8 ah, al, bh, bl;
    split8(ap + kk * 32, ah, al);
    split8(bp + kk * 32, bh, bl);
    acc = __builtin_amdgcn_mfma_f32_16x16x32_bf16(ah, bh, acc, 0, 0, 0);
    acc = __builtin_amdgcn_mfma_f32_16x16x32_bf16(ah, bl, acc, 0, 0, 0);
    acc = __builtin_amdgcn_mfma_f32_16x16x32_bf16(al, bh, acc, 0, 0, 0);
  }
#pragma unroll
  for (int r = 0; r < 4; ++r) {
    const int mo = blockIdx.y * 16 + lk * 4 + r;   // C/D: row=(lane>>4)*4+reg
    if (mo < VOCAB_) {
      if constexpr (sizeof(ET) == 2)
        encg[(size_t)mo * 2048 + n] = (ET)f2bfbits(acc[r]);
      else
        encg[(size_t)mo * 2048 + n] = acc[r];       // col = lane&15
    }
  }
}

// ---------------------------------------------------------------------------
// K2: et[s][b] = sigmoid(P[u].Q[k] + Pb[u] + Qb[k]); f32. grid (200,128)x256.
// ---------------------------------------------------------------------------
__global__ void mf_kernel(const int* __restrict__ us, const int* __restrict__ ss,
                          const float* __restrict__ P, const float* __restrict__ Q,
                          const float* __restrict__ Pb, const float* __restrict__ Qb,
                          float* __restrict__ etb) {
  const int s = blockIdx.x;
  const int w = threadIdx.x >> 6, l = threadIdx.x & 63;
  const int b = blockIdx.y * 4 + w;
  const int u = us[b * S_ + s];
  const int k = ss[b * S_ + s];
  const float4 p0 = *(const float4*)(P + (size_t)u * 512 + l * 8);
  const float4 p1 = *(const float4*)(P + (size_t)u * 512 + l * 8 + 4);
  const float4 q0 = *(const float4*)(Q + (size_t)k * 512 + l * 8);
  const float4 q1 = *(const float4*)(Q + (size_t)k * 512 + l * 8 + 4);
  float dot = p0.x*q0.x + p0.y*q0.y + p0.z*q0.z + p0.w*q0.w
            + p1.x*q1.x + p1.y*q1.y + p1.z*q1.z + p1.w*q1.w;
#pragma unroll
  for (int off = 32; off > 0; off >>= 1) dot += __shfl_xor(dot, off);
  if (l == 0)
    etb[s * B_ + b] = sigmoidf_(dot + Pb[u] + Qb[k]);
}

// ---------------------------------------------------------------------------
// K3: recurrent LSTM, f32-accurate. 256 blocks x 512 thr, 1 block/CU.
// group g=bid&15 owns 32 batch rows; slice ns=bid>>4 owns 32 h-units.
//
// r14 = r11 (last PASSING kernel; XCD experiment dropped after 2 container
// failures) + staging address remap to kill the 2x uncached over-fetch:
//  - OLD: thread (sr,sc) read its 32B chunk as dwordx4 @ sc*32 and @ sc*32+16.
//    Per wave-instruction, lanes read 16B at STRIDE 32 -> each 64B line is
//    touched by BOTH instructions; sc0 sc1 loads don't cache, so every line
//    was fetched TWICE (measured: FETCH 7.25GB vs 3.28GB payload + gathers).
//  - NEW: thread (sr,sc) loads four 16B chunks per array at ushort offsets
//    sc*8 + j*128 (j=0..3). Each instruction's row-footprint is a contiguous
//    256B -> every 64B line belongs to exactly one instruction, fetched once;
//    full-line transactions, half the transaction count.
//  - LDS image unchanged: chunk at col-group g8 lands at g8 ^ swzw (the XOR
//    operates on 8-ushort=16B granules, aligned with chunks) -> MFMA readers
//    byte-identical to r11. Issue order (4 h0 loads, then 4 h1) preserves
//    the vmcnt(4) split pipeline.
// ---------------------------------------------------------------------------
template <typename ET>
__global__ __launch_bounds__(512, 2) void lstm_kernel(
    const int* __restrict__ tok, const ET* __restrict__ encg,
    const float* __restrict__ etb, const float* __restrict__ Whh,
    const float* __restrict__ bih, const float* __restrict__ bhh,
    ushort* ht_hi, ushort* ht_lo, int* ctr) {
  __shared__ __align__(16) ushort Ah_lds[32 * 512];   // 32,768 B (XOR-swizzled)
  __shared__ __align__(16) ushort Al_lds[32 * 512];   // 32,768 B
  __shared__ float gp_lds[2 * 128 * 33];              // 33,792 B

  const int bid = blockIdx.x;
  const int g = bid & 15, ns = bid >> 4;
  const int b0 = g * 32, h0 = ns * 32;
  const int tid = threadIdx.x;
  const int w = tid >> 6, l = tid & 63;
  const int nt = w & 3;                 // gate tile (i,f,g,o)
  const int kh = w >> 2;                // K-half (0: cols 0..255, 1: 256..511)

  // slots: group g's 16 producer blocks publish at ctr[g*16 + ns] -- one
  // 64-B line per group, one dword per block.
  int* const myslot = ctr + g * 16 + ns;
  const int* const gslots = ctr + g * 16;

  // --- preload + split this wave's W_hh rows (32 gate cols, its K-half) ---
  // B operand 32x32x16: lane l holds col=l&31, k=(l>>5)*8+j.
  short8 Bh[16], Bl[16];
  {
    const float* wr = Whh + (size_t)(nt * 512 + h0 + (l & 31)) * 512
                    + kh * 256 + (l >> 5) * 8;
#pragma unroll 4
    for (int kk = 0; kk < 16; ++kk)
      split8(wr + kk * 16, Bh[kk], Bl[kk]);
  }

  const int sr = tid >> 4;              // batch row within group (0..31)
  const int sc = tid & 15;              // 16 stagers per row
  const int hh = sc * 2;
  const int bg = b0 + sr;
  float ct0 = 0.f, ct1 = 0.f;

  float bs[4][2];
#pragma unroll
  for (int qq = 0; qq < 4; ++qq) {
    const int col = qq * 512 + h0 + hh;
    bs[qq][0] = bih[col] + bhh[col];
    bs[qq][1] = bih[col + 1] + bhh[col + 1];
  }

  const int swzw = (sr & 7) << 3;       // writer swizzle (ushort units)
  const int swzr = (l & 7) << 3;        // reader swizzle (row = l&31 -> row&7 = l&7)
  const int k8 = (l >> 5) * 8;          // lane's k-offset within 16-wide step
  const int sc8 = sc * 8;               // this thread's base chunk col (ushorts)

  // 48 MFMAs over one K-half; A row = l&31 from swizzled LDS.
  auto mfma_half = [&](int base) -> floatx16 {
    floatx16 a = {0.f,0.f,0.f,0.f,0.f,0.f,0.f,0.f,
                  0.f,0.f,0.f,0.f,0.f,0.f,0.f,0.f};
#pragma unroll
    for (int kk = 0; kk < 16; ++kk) {
      const int ao = (l & 31) * 512 + ((base + kk * 16 + k8) ^ swzr);
      const short8 ah = *(const short8*)(Ah_lds + ao);
      const short8 al = *(const short8*)(Al_lds + ao);
      a = __builtin_amdgcn_mfma_f32_32x32x16_bf16(ah, Bh[kk], a, 0, 0, 0);
      a = __builtin_amdgcn_mfma_f32_32x32x16_bf16(ah, Bl[kk], a, 0, 0, 0);
      a = __builtin_amdgcn_mfma_f32_32x32x16_bf16(al, Bh[kk], a, 0, 0, 0);
    }
    return a;
  };
  // C/D 32x32: col = lane&31, row = (reg&3) + 8*(reg>>2) + 4*(lane>>5)
  auto gp_write = [&](const floatx16& a) {
    float* gpw = gp_lds + kh * 4224 + (nt * 32 + (l & 31)) * 33 + 4 * (l >> 5);
#pragma unroll
    for (int r = 0; r < 16; ++r)
      gpw[(r & 3) + 8 * (r >> 2)] = a[r];
  };

  for (int s = 0; s < S_; ++s) {
    // ---- prefetch nonlinearity inputs (ht-independent; hides under spin) ----
    const int tv = tok[bg * S_ + s];
    float ev = etb[s * B_ + bg];
    float ex[4], ey[4];
#pragma unroll
    for (int qq = 0; qq < 4; ++qq) {
      if constexpr (sizeof(ET) == 2) {
        const uint e2 = *(const uint*)((const ushort*)encg + (size_t)tv * 2048 + qq * 512 + h0 + hh);
        ex[qq] = bf2f_((ushort)(e2 & 0xffffu)); ey[qq] = bf2f_((ushort)(e2 >> 16));
      } else {
        const float2 e = *(const float2*)((const float*)encg + (size_t)tv * 2048 + qq * 512 + h0 + hh);
        ex[qq] = e.x; ey[qq] = e.y;
      }
    }

    // ---- wait: all 16 producer blocks of this group must have published s.
    // One 64B line; lane tid polls dword tid -> one coalesced request/iter.
    if (s > 0 && tid < 16) {
      const int* sp = gslots + tid;
      while (ld4_cc_wait(sp) < s) {}
    }
    __syncthreads();                                     // bar A

    const size_t rdo = (size_t)(s & 1) * (B_ * H_);
    const size_t wro = (size_t)((s & 1) ^ 1) * (B_ * H_);
    const ushort* hrow = ht_hi + rdo + (size_t)bg * 512;
    const ushort* lrow = ht_lo + rdo + (size_t)bg * 512;

    // ---- issue ALL staging loads (interleaved chunks: instruction j covers
    // a contiguous 256B per row -> no over-fetch); vmcnt(4) drains h0 only.
    uintx4 a0, a1, b0_, b1_;            // h0: hi j0,j1 + lo j0,j1
    uintx4 a2, a3, b2_, b3_;            // h1: hi j2,j3 + lo j2,j3
    __builtin_amdgcn_sched_barrier(0);
    ld16_cc(hrow + sc8,       a0);
    ld16_cc(hrow + sc8 + 128, a1);
    ld16_cc(lrow + sc8,       b0_);
    ld16_cc(lrow + sc8 + 128, b1_);
    ld16_cc(hrow + sc8 + 256, a2);
    ld16_cc(hrow + sc8 + 384, a3);
    ld16_cc(lrow + sc8 + 256, b2_);
    ld16_cc(lrow + sc8 + 384, b3_);
    vm_wait4();                          // oldest 4 (h0) complete
    __builtin_amdgcn_sched_barrier(0);
    {
      const int base = sr * 512;
      *(uintx4*)(Ah_lds + base + (sc8 ^ swzw))         = a0;
      *(uintx4*)(Ah_lds + base + ((sc8 + 128) ^ swzw)) = a1;
      *(uintx4*)(Al_lds + base + (sc8 ^ swzw))         = b0_;
      *(uintx4*)(Al_lds + base + ((sc8 + 128) ^ swzw)) = b1_;
    }
    __syncthreads();                                     // bar B (h0 staged)

    floatx16 acc;
    if (kh == 0) {
      acc = mfma_half(0);               // reads h0 half of LDS
      gp_write(acc);
      vm_wait0();                        // h1 long since arrived
      __builtin_amdgcn_sched_barrier(0);
      const int base = sr * 512;
      *(uintx4*)(Ah_lds + base + ((sc8 + 256) ^ swzw)) = a2;
      *(uintx4*)(Ah_lds + base + ((sc8 + 384) ^ swzw)) = a3;
      *(uintx4*)(Al_lds + base + ((sc8 + 256) ^ swzw)) = b2_;
      *(uintx4*)(Al_lds + base + ((sc8 + 384) ^ swzw)) = b3_;
    } else {
      vm_wait0();
      __builtin_amdgcn_sched_barrier(0);
      const int base = sr * 512;
      *(uintx4*)(Ah_lds + base + ((sc8 + 256) ^ swzw)) = a2;
      *(uintx4*)(Ah_lds + base + ((sc8 + 384) ^ swzw)) = a3;
      *(uintx4*)(Al_lds + base + ((sc8 + 256) ^ swzw)) = b2_;
      *(uintx4*)(Al_lds + base + ((sc8 + 384) ^ swzw)) = b3_;
    }
    __syncthreads();                                     // bar C (h1 staged)

    if (kh == 1) {
      acc = mfma_half(256);             // reads h1 half of LDS
      gp_write(acc);
    }
    __syncthreads();                                     // bar D (gp complete)

    // ---- nonlinearity: thread owns (row sr, h-units hh, hh+1) ----
    {
      ev = fminf(fmaxf(ev, 0.f), 1.f);
      float Gv[4][2];
#pragma unroll
      for (int qq = 0; qq < 4; ++qq) {
        const int cb0 = (qq * 32 + hh) * 33 + sr;
        const int cb1 = (qq * 32 + hh + 1) * 33 + sr;
        Gv[qq][0] = clamp30(gp_lds[cb0] + gp_lds[4224 + cb0] + ex[qq] + bs[qq][0]);
        Gv[qq][1] = clamp30(gp_lds[cb1] + gp_lds[4224 + cb1] + ey[qq] + bs[qq][1]);
      }
      const float scale = 1.f + ev;
      float c0v = ct0 * scale;
      c0v = sigmoidf_(Gv[1][0]) * c0v + sigmoidf_(Gv[0][0]) * tanhf_(Gv[2][0]);
      const float h0v = sigmoidf_(Gv[3][0]) * tanhf_(c0v);
      ct0 = c0v;                                   // UNCLAMPED (ref semantics)
      float c1v = ct1 * scale;
      c1v = sigmoidf_(Gv[1][1]) * c1v + sigmoidf_(Gv[0][1]) * tanhf_(Gv[2][1]);
      const float h1v = sigmoidf_(Gv[3][1]) * tanhf_(c1v);
      ct1 = c1v;
      const ushort h0h = f2bfbits(h0v), h1h = f2bfbits(h1v);
      const ushort h0l = f2bfbits(h0v - bf2f_(h0h)), h1l = f2bfbits(h1v - bf2f_(h1h));
      const size_t wo = wro + (size_t)bg * 512 + h0 + hh;
      __hip_atomic_store((uint*)(ht_hi + wo), (uint)h0h | ((uint)h1h << 16),
                         __ATOMIC_RELAXED, __HIP_MEMORY_SCOPE_AGENT);
      __hip_atomic_store((uint*)(ht_lo + wo), (uint)h0l | ((uint)h1l << 16),
                         __ATOMIC_RELAXED, __HIP_MEMORY_SCOPE_AGENT);
    }

    // ---- per-block publish: every wave drains its ht stores to the
    // coherence point (vmcnt0), barrier proves ALL waves drained, then one
    // tid0 store flips the group-visible slot to s+1.
    vm_wait0();
    __syncthreads();                                     // bar E (all drained)
    if (tid == 0)
      __hip_atomic_store(myslot, s + 1, __ATOMIC_RELAXED, __HIP_MEMORY_SCOPE_AGENT);
  }
}

// ---------------------------------------------------------------------------
// K4: out[b] = sigmoid( (ht_hi+ht_lo)[b] . dec_W[tgt[b]] + dec_b[tgt[b]] )
// grid 128 x 256 (one wave per batch row). Final ht is in buffer parity 0.
// ---------------------------------------------------------------------------
__global__ void dec_kernel(const ushort* __restrict__ hthi, const ushort* __restrict__ htlo,
                           const float* __restrict__ decW, const float* __restrict__ decb,
                           const int* __restrict__ tgt, float* __restrict__ out) {
  const int w = threadIdx.x >> 6, l = threadIdx.x & 63;
  const int b = blockIdx.x * 4 + w;
  const int t = tgt[b];
  const uint4 hv = *(const uint4*)(hthi + (size_t)b * 512 + l * 8);
  const uint4 lv = *(const uint4*)(htlo + (size_t)b * 512 + l * 8);
  const float4 w0 = *(const float4*)(decW + (size_t)t * 512 + l * 8);
  const float4 w1 = *(const float4*)(decW + (size_t)t * 512 + l * 8 + 4);
  const uint ha[4] = {hv.x, hv.y, hv.z, hv.w};
  const uint la[4] = {lv.x, lv.y, lv.z, lv.w};
  float hf[8];
#pragma unroll
  for (int i = 0; i < 4; ++i) {
    hf[2*i]   = bf2f_((ushort)(ha[i] & 0xffffu)) + bf2f_((ushort)(la[i] & 0xffffu));
    hf[2*i+1] = bf2f_((ushort)(ha[i] >> 16))     + bf2f_((ushort)(la[i] >> 16));
  }
  float dot = hf[0]*w0.x + hf[1]*w0.y + hf[2]*w0.z + hf[3]*w0.w
            + hf[4]*w1.x + hf[5]*w1.y + hf[6]*w1.z + hf[7]*w1.w;
#pragma unroll
  for (int off = 32; off > 0; off >>= 1) dot += __shfl_xor(dot, off);
  if (l == 0) out[b] = sigmoidf_(dot + decb[t]);
}

extern "C" void kernel_launch(void* const* d_in, const int* in_sizes, int n_in,
                              void* d_out, int out_size, void* d_ws, size_t ws_size,
                              hipStream_t stream) {
  (void)in_sizes; (void)n_in; (void)out_size;
  const int* main_input = (const int*)d_in[0];
  const int* target_id  = (const int*)d_in[1];
  const int* user_seq   = (const int*)d_in[2];
  const int* skill_seq  = (const int*)d_in[3];
  const float* enc_emb  = (const float*)d_in[4];
  const float* P        = (const float*)d_in[5];
  const float* Q        = (const float*)d_in[6];
  const float* Pb       = (const float*)d_in[7];
  const float* Qb       = (const float*)d_in[8];
  const float* W_ih     = (const float*)d_in[9];
  const float* W_hh     = (const float*)d_in[10];
  const float* b_ih     = (const float*)d_in[11];
  const float* b_hh     = (const float*)d_in[12];
  const float* dec_W    = (const float*)d_in[13];
  const float* dec_b    = (const float*)d_in[14];
  float* out = (float*)d_out;

  // workspace layout (unchanged):
  //   [0)          ht_hi  2*512*512 bf16 = 1,048,576
  //   [1,048,576)  ht_lo  1,048,576                  -> 2,097,152
  //   [2,097,152)  ctr    256 ints used (16 lines)   -> 2,113,536 (region)
  //   [2,113,536)  etb    200*512 f32 = 409,600      -> 2,523,136
  //   [2,523,136)  encg   f32 16,400,384 (else bf16 8,200,192)
  char* wsb = (char*)d_ws;
  ushort* ht_hi = (ushort*)wsb;
  ushort* ht_lo = (ushort*)(wsb + 1048576);
  int* ctr = (int*)(wsb + 2097152);
  float* etb = (float*)(wsb + 2113536);
  char* encb = wsb + 2523136;
  const bool enc32 = ws_size >= (size_t)2523136 + 16400384;

  hipMemsetAsync(wsb, 0, 2113536, stream);   // ht(0)=0, all slots=0

  if (enc32)
    encg_kernel<float><<<dim3(32, 126), dim3(256), 0, stream>>>(enc_emb, W_ih, (float*)encb);
  else
    encg_kernel<ushort><<<dim3(32, 126), dim3(256), 0, stream>>>(enc_emb, W_ih, (ushort*)encb);
  mf_kernel<<<dim3(200, 128), dim3(256), 0, stream>>>(user_seq, skill_seq, P, Q, Pb, Qb, etb);
  if (enc32)
    lstm_kernel<float><<<dim3(256), dim3(512), 0, stream>>>(
        main_input, (const float*)encb, etb, W_hh, b_ih, b_hh, ht_hi, ht_lo, ctr);
  else
    lstm_kernel<ushort><<<dim3(256), dim3(512), 0, stream>>>(
        main_input, (const ushort*)encb, etb, W_hh, b_ih, b_hh, ht_hi, ht_lo, ctr);
  dec_kernel<<<dim3(128), dim3(256), 0, stream>>>(ht_hi, ht_lo, dec_W, dec_b, target_id, out);
}